// Round 11
// baseline (167.435 us; speedup 1.0000x reference)
//
#include <hip/hip_runtime.h>
#include <hip/hip_bf16.h>
#include <math.h>

#define HD 256
#define BB 64
#define DD 2048
#define NCHK 8          // 256-row chunks per batch

typedef __attribute__((ext_vector_type(8))) short  short8;
typedef __attribute__((ext_vector_type(4))) float  float4v;
typedef __attribute__((ext_vector_type(4))) unsigned uint4v;
typedef __attribute__((ext_vector_type(4))) unsigned short ushort4v;

__device__ inline unsigned short f2bf(float f) {
    unsigned u = __builtin_bit_cast(unsigned, f);
    u += 0x7FFFu + ((u >> 16) & 1u);   // RNE
    return (unsigned short)(u >> 16);
}

__device__ inline unsigned cvt_pk_bf16(float lo, float hi) {
    unsigned r;
    asm("v_cvt_pk_bf16_f32 %0, %1, %2" : "=v"(r) : "v"(lo), "v"(hi));
    return r;
}
__device__ inline short8 cvt8(float4v lo, float4v hi) {
    uint4v u;
    u[0] = cvt_pk_bf16(lo[0], lo[1]);
    u[1] = cvt_pk_bf16(lo[2], lo[3]);
    u[2] = cvt_pk_bf16(hi[0], hi[1]);
    u[3] = cvt_pk_bf16(hi[2], hi[3]);
    return __builtin_bit_cast(short8, u);
}

__device__ inline float fast_exp2(float x) {
    float r;
    asm("v_exp_f32 %0, %1" : "=v"(r) : "v"(x));
    return r;
}
__device__ inline float fast_expf(float x) { return fast_exp2(x * 1.4426950408889634f); }
__device__ inline float fast_tanh(float x) {
    float y = x * 2.8853900817779268f;          // 2x * log2(e)
    y = fminf(fmaxf(y, -30.f), 30.f);
    float t = fast_exp2(y);
    float r;
    asm("v_rcp_f32 %0, %1" : "=v"(r) : "v"(t + 1.f));
    return (t - 1.f) * r;
}

#define SYNC_LDS() do { asm volatile("s_waitcnt lgkmcnt(0)" ::: "memory"); \
                        __builtin_amdgcn_s_barrier(); \
                        asm volatile("" ::: "memory"); } while (0)

// ---------------- kernel 0 (fused prep): W1 f32->bf16  AND  g23 ----------------
__global__ __launch_bounds__(256) void k_prep(const float* __restrict__ W1,
                                              unsigned short* __restrict__ w1b,
                                              const float* __restrict__ ctx,
                                              const float* __restrict__ hid,
                                              const float* __restrict__ W2,
                                              const float* __restrict__ b2,
                                              const float* __restrict__ W3,
                                              float* __restrict__ g23) {
    if (blockIdx.x < 64) {
        int i = blockIdx.x * 256 + threadIdx.x;
        float4v v = ((const float4v*)W1)[i];
        ushort4v o;
        o[0] = f2bf(v[0]); o[1] = f2bf(v[1]); o[2] = f2bf(v[2]); o[3] = f2bf(v[3]);
        ((ushort4v*)w1b)[i] = o;
    } else {
        int b = blockIdx.x - 64, t = threadIdx.x;
        __shared__ float c[HD], hh[HD];
        c[t]  = ctx[b * HD + t];
        hh[t] = hid[b * HD + t];
        __syncthreads();
        const float4v* w2 = (const float4v*)(W2 + (size_t)t * HD);
        const float4v* w3 = (const float4v*)(W3 + (size_t)t * HD);
        float acc = b2[t];
        #pragma unroll 8
        for (int k = 0; k < 64; ++k) {
            float4v a = w2[k], d = w3[k];
            int k4 = k * 4;
            acc += c[k4] * a[0] + c[k4 + 1] * a[1] + c[k4 + 2] * a[2] + c[k4 + 3] * a[3];
            acc += hh[k4] * d[0] + hh[k4 + 1] * d[1] + hh[k4 + 2] * d[2] + hh[k4 + 3] * d[3];
        }
        g23[b * HD + t] = acc;
    }
}

// ---------------- kernel 1: scores = W4 . tanh(q@W1^T + g23), barrier-free -----
// grid (8, 64), 512 thr (8 free-running waves). Wave owns 32 h (bfr = 64 VGPR)
// and streams ALL 16 d-blocks of the 256-row chunk DIRECTLY from global to
// MFMA B-fragments (no LDS tile, no per-tile barrier). Wave 0 pulls HBM;
// waves 1-7 ride L1/L2. Partial scores -> wave-private sp_acc row; single
// barrier + 8-way sum at kernel end.
__global__ __launch_bounds__(512) void k_scores(const float* __restrict__ q,
                                                const unsigned short* __restrict__ w1b,
                                                const float* __restrict__ g23,
                                                const float* __restrict__ W4,
                                                float* __restrict__ scores) {
    __shared__ float sp_acc[8][HD];   // 8 KB; wave-private rows

    const int t = threadIdx.x;
    const int chunk = blockIdx.x, b = blockIdx.y;
    const int lane = t & 63, wave = t >> 6;
    const int l15 = lane & 15, lk = lane >> 4;
    const int hb = wave * 32;

    const float* qc = q + ((size_t)b * DD + chunk * 256) * HD;

    // W1 slice (A operand) -> 64 VGPR (L2-hot after k_prep)
    short8 bfr[8][2];
    #pragma unroll
    for (int kb = 0; kb < 8; ++kb)
        #pragma unroll
        for (int nf = 0; nf < 2; ++nf)
            bfr[kb][nf] = *(const short8*)&w1b[(size_t)(hb + nf * 16 + l15) * HD + kb * 32 + lk * 8];

    // per-lane g23/W4 for C rows h = hb + nf*16 + lk*4 + r
    float gv[2][4], wv[2][4];
    #pragma unroll
    for (int nf = 0; nf < 2; ++nf)
        #pragma unroll
        for (int r = 0; r < 4; ++r) {
            int h = hb + nf * 16 + lk * 4 + r;
            gv[nf][r] = g23[b * HD + h];
            wv[nf][r] = W4[h];
        }

    // this lane's q row within each 16-row d-block, and its 32B k-slice offset
    const float* qrow = qc + (size_t)l15 * HD + lk * 8;

    #pragma unroll 1
    for (int db = 0; db < 16; ++db) {
        const float* qd = qrow + (size_t)db * 16 * HD;

        // 16 independent global dwordx4 loads (B-fragments, f32)
        float4v qf[8][2];
        #pragma unroll
        for (int kb = 0; kb < 8; ++kb) {
            qf[kb][0] = *(const float4v*)(qd + kb * 32);
            qf[kb][1] = *(const float4v*)(qd + kb * 32 + 4);
        }

        float4v a0 = {0.f, 0.f, 0.f, 0.f}, a1 = {0.f, 0.f, 0.f, 0.f};
        #pragma unroll
        for (int kb = 0; kb < 8; ++kb) {
            short8 bq = cvt8(qf[kb][0], qf[kb][1]);
            a0 = __builtin_amdgcn_mfma_f32_16x16x32_bf16(bfr[kb][0], bq, a0, 0, 0, 0);
            a1 = __builtin_amdgcn_mfma_f32_16x16x32_bf16(bfr[kb][1], bq, a1, 0, 0, 0);
        }

        float s = 0.f;
        #pragma unroll
        for (int r = 0; r < 4; ++r) s += fast_tanh(a0[r] + gv[0][r]) * wv[0][r];
        #pragma unroll
        for (int r = 0; r < 4; ++r) s += fast_tanh(a1[r] + gv[1][r]) * wv[1][r];
        s += __shfl_xor(s, 16, 64);
        s += __shfl_xor(s, 32, 64);
        if (lane < 16) sp_acc[wave][db * 16 + lane] = s;
    }

    // single cross-wave reduction at kernel end
    SYNC_LDS();
    if (t < HD) {
        float s = sp_acc[0][t] + sp_acc[1][t] + sp_acc[2][t] + sp_acc[3][t]
                + sp_acc[4][t] + sp_acc[5][t] + sp_acc[6][t] + sp_acc[7][t];
        scores[b * DD + chunk * 256 + t] = s;   // b4 dropped (softmax shift-inv)
    }
}

// ---------------- kernel 2: per-batch softmax stats ----------------
__global__ __launch_bounds__(256) void k_stats(const float* __restrict__ scores,
                                               float* __restrict__ stats) {
    int b = blockIdx.x, t = threadIdx.x;
    __shared__ float red[256];
    float sv[8];
    float lm = -1e30f;
    #pragma unroll
    for (int i = 0; i < 8; ++i) {
        sv[i] = scores[b * DD + t + i * 256];
        lm = fmaxf(lm, sv[i]);
    }
    red[t] = lm; __syncthreads();
    for (int s = 128; s > 0; s >>= 1) {
        if (t < s) red[t] = fmaxf(red[t], red[t + s]);
        __syncthreads();
    }
    float mx = red[0];
    __syncthreads();
    float ls = 0.f;
    #pragma unroll
    for (int i = 0; i < 8; ++i) ls += fast_expf(sv[i] - mx);
    red[t] = ls; __syncthreads();
    for (int s = 128; s > 0; s >>= 1) {
        if (t < s) red[t] += red[t + s];
        __syncthreads();
    }
    if (t == 0) { stats[b * 2] = mx; stats[b * 2 + 1] = 1.f / red[0]; }
}

// ---------------- kernel 3: partial weighted sums (L3-hot second q pass) -------
__global__ __launch_bounds__(256) void k_pout(const float* __restrict__ q,
                                              const float* __restrict__ scores,
                                              const float* __restrict__ stats,
                                              float* __restrict__ part) {
    const int b = blockIdx.y, ch = blockIdx.x, t = threadIdx.x;
    __shared__ float wl[256];
    __shared__ float4v red[256];
    const float mx = stats[b * 2], inv = stats[b * 2 + 1];
    const int d0 = ch * 256;
    wl[t] = fast_expf(scores[b * DD + d0 + t] - mx) * inv;
    __syncthreads();
    const int rg = t >> 6, cg = t & 63;       // row-group, col-float4
    const float4v* qb = (const float4v*)(q + ((size_t)(b * DD + d0 + rg)) * HD) + cg;
    float4v a0 = {0,0,0,0}, a1 = {0,0,0,0};
    #pragma unroll 8
    for (int i = 0; i < 64; i += 2) {
        a0 += qb[(size_t)i * 256]       * wl[rg + i * 4];
        a1 += qb[(size_t)(i + 1) * 256] * wl[rg + (i + 1) * 4];
    }
    red[t] = a0 + a1;
    __syncthreads();
    if (t < 64) {
        float4v s = red[t] + red[t + 64] + red[t + 128] + red[t + 192];
        ((float4v*)part)[((size_t)(b * 8 + ch)) * 64 + t] = s;
    }
}

// ---------------- kernel 4: reduce partials ----------------
__global__ __launch_bounds__(64) void k_rout(const float* __restrict__ part,
                                             float* __restrict__ out) {
    int b = blockIdx.x, t = threadIdx.x;
    float4v s = {0,0,0,0};
    #pragma unroll
    for (int c = 0; c < 8; ++c) s += ((const float4v*)part)[((size_t)(b * 8 + c)) * 64 + t];
    ((float4v*)out)[b * 64 + t] = s;
}

extern "C" void kernel_launch(void* const* d_in, const int* in_sizes, int n_in,
                              void* d_out, int out_size, void* d_ws, size_t ws_size,
                              hipStream_t stream) {
    (void)in_sizes; (void)n_in; (void)out_size; (void)ws_size;
    const float* ctx = (const float*)d_in[0];
    const float* q   = (const float*)d_in[1];
    const float* hid = (const float*)d_in[2];
    const float* W1  = (const float*)d_in[3];
    const float* W2  = (const float*)d_in[4];
    const float* b2  = (const float*)d_in[5];
    const float* W3  = (const float*)d_in[6];
    const float* W4  = (const float*)d_in[7];
    // d_in[8] = b4: dropped (softmax shift-invariant)
    float* out = (float*)d_out;

    char* ws = (char*)d_ws;
    unsigned short* w1b = (unsigned short*)(ws);            // 131072 B
    float* g23    = (float*)(ws + 131072);                  //  65536 B
    float* scores = (float*)(ws + 196608);                  // 524288 B
    float* stats  = (float*)(ws + 720896);                  //    512 B
    float* part   = (float*)(ws + 721408);                  // 524288 B

    k_prep  <<<dim3(128), dim3(256), 0, stream>>>(W1, w1b, ctx, hid, W2, b2, W3, g23);
    k_scores<<<dim3(NCHK, BB), dim3(512), 0, stream>>>(q, w1b, g23, W4, scores);
    k_stats <<<dim3(BB), dim3(256), 0, stream>>>(scores, stats);
    k_pout  <<<dim3(8, BB), dim3(256), 0, stream>>>(q, scores, stats, part);
    k_rout  <<<dim3(BB), dim3(64), 0, stream>>>(part, out);
}

// Round 12
// 89.326 us; speedup vs baseline: 1.8744x; 1.8744x over previous
//
#include <hip/hip_runtime.h>
#include <hip/hip_bf16.h>
#include <math.h>

#define HD 256
#define BB 64
#define DD 2048
#define NCHK 8          // 256-row chunks per batch
#define NT 8            // 32-row sub-tiles per chunk

typedef __attribute__((ext_vector_type(8))) short  short8;
typedef __attribute__((ext_vector_type(4))) float  float4v;
typedef __attribute__((ext_vector_type(4))) unsigned uint4v;
typedef __attribute__((ext_vector_type(4))) unsigned short ushort4v;

__device__ inline unsigned short f2bf(float f) {
    unsigned u = __builtin_bit_cast(unsigned, f);
    u += 0x7FFFu + ((u >> 16) & 1u);   // RNE
    return (unsigned short)(u >> 16);
}

__device__ inline unsigned cvt_pk_bf16(float lo, float hi) {
    unsigned r;
    asm("v_cvt_pk_bf16_f32 %0, %1, %2" : "=v"(r) : "v"(lo), "v"(hi));
    return r;
}
__device__ inline short8 cvt8(float4v lo, float4v hi) {
    uint4v u;
    u[0] = cvt_pk_bf16(lo[0], lo[1]);
    u[1] = cvt_pk_bf16(lo[2], lo[3]);
    u[2] = cvt_pk_bf16(hi[0], hi[1]);
    u[3] = cvt_pk_bf16(hi[2], hi[3]);
    return __builtin_bit_cast(short8, u);
}

__device__ inline float fast_exp2(float x) {
    float r;
    asm("v_exp_f32 %0, %1" : "=v"(r) : "v"(x));
    return r;
}
__device__ inline float fast_expf(float x) { return fast_exp2(x * 1.4426950408889634f); }
__device__ inline float fast_tanh(float x) {
    float y = x * 2.8853900817779268f;          // 2x * log2(e)
    y = fminf(fmaxf(y, -30.f), 30.f);
    float t = fast_exp2(y);
    float r;
    asm("v_rcp_f32 %0, %1" : "=v"(r) : "v"(t + 1.f));
    return (t - 1.f) * r;
}

// LDS-only barrier: orders LDS traffic without draining vmcnt.
#define SYNC_LDS() do { asm volatile("s_waitcnt lgkmcnt(0)" ::: "memory"); \
                        __builtin_amdgcn_s_barrier(); \
                        asm volatile("" ::: "memory"); } while (0)
#define WAITV4()  asm volatile("s_waitcnt vmcnt(4)" ::: "memory")
#define WAITV0()  asm volatile("s_waitcnt vmcnt(0)" ::: "memory")
#define BARRIER() do { __builtin_amdgcn_s_barrier(); asm volatile("" ::: "memory"); } while (0)

__device__ inline void load_lds16(const void* g, void* l) {
    __builtin_amdgcn_global_load_lds(
        (const __attribute__((address_space(1))) void*)g,
        (__attribute__((address_space(3))) void*)l, 16, 0, 0);
}

// stage one 32-row f32 sub-tile; wave stages rows [wave*4, wave*4+4).
// Source pre-swizzled on 32B granules (g ^= r&7); LDS dest linear (rule 21):
// gload_lds writes base + lane*16.
__device__ inline void stage32(const float* qtile, float* buf, int wave, int lane) {
    const int half = lane & 1;
    #pragma unroll
    for (int i = 0; i < 4; ++i) {
        int r = wave * 4 + i;
        int gsrc = ((((lane >> 1) ^ (r & 7)) << 1) | half) << 4;   // byte in row
        load_lds16((const char*)qtile + (size_t)r * 1024 + gsrc,
                   (char*)buf + r * 1024);
    }
}

// ---------------- kernel 0 (fused prep): W1 f32->bf16  AND  g23 ----------------
__global__ __launch_bounds__(256) void k_prep(const float* __restrict__ W1,
                                              unsigned short* __restrict__ w1b,
                                              const float* __restrict__ ctx,
                                              const float* __restrict__ hid,
                                              const float* __restrict__ W2,
                                              const float* __restrict__ b2,
                                              const float* __restrict__ W3,
                                              float* __restrict__ g23) {
    if (blockIdx.x < 64) {
        int i = blockIdx.x * 256 + threadIdx.x;
        float4v v = ((const float4v*)W1)[i];
        ushort4v o;
        o[0] = f2bf(v[0]); o[1] = f2bf(v[1]); o[2] = f2bf(v[2]); o[3] = f2bf(v[3]);
        ((ushort4v*)w1b)[i] = o;
    } else {
        int b = blockIdx.x - 64, t = threadIdx.x;
        __shared__ float c[HD], hh[HD];
        c[t]  = ctx[b * HD + t];
        hh[t] = hid[b * HD + t];
        __syncthreads();
        const float4v* w2 = (const float4v*)(W2 + (size_t)t * HD);
        const float4v* w3 = (const float4v*)(W3 + (size_t)t * HD);
        float acc = b2[t];
        #pragma unroll 8
        for (int k = 0; k < 64; ++k) {
            float4v a = w2[k], d = w3[k];
            int k4 = k * 4;
            acc += c[k4] * a[0] + c[k4 + 1] * a[1] + c[k4 + 2] * a[2] + c[k4 + 3] * a[3];
            acc += hh[k4] * d[0] + hh[k4 + 1] * d[1] + hh[k4 + 2] * d[2] + hh[k4 + 3] * d[3];
        }
        g23[b * HD + t] = acc;
    }
}

// ---------------- kernel 1: scores = W4 . tanh(q@W1^T + g23) -------------------
// grid (8, 64) = 512 blocks = 2/CU (LDS 73KB). 512 thr, 8 waves; wave owns 32 h
// (bfr = 64 VGPR). Round-8 schedule: gload_lds f32 staging, counted vmcnt(4),
// 2 LDS-only barriers per sub-tile; wave-private sp_acc rows (no passB).
__global__ __launch_bounds__(512) void k_scores(const float* __restrict__ q,
                                                const unsigned short* __restrict__ w1b,
                                                const float* __restrict__ g23,
                                                const float* __restrict__ W4,
                                                float* __restrict__ scores) {
    __shared__ __attribute__((aligned(16))) float buf0[32 * HD];   // 32 KB
    __shared__ __attribute__((aligned(16))) float buf1[32 * HD];   // 32 KB
    __shared__ float sp_acc[8][HD];                                // 8 KB

    const int t = threadIdx.x;
    const int chunk = blockIdx.x, b = blockIdx.y;
    const int lane = t & 63, wave = t >> 6;
    const int l15 = lane & 15, lk = lane >> 4;
    const int hb = wave * 32;

    const float* qc = q + ((size_t)b * DD + chunk * 256) * HD;

    // issue sub-tile 0 immediately
    stage32(qc, buf0, wave, lane);

    // W1 slice (A operand) -> 64 VGPR (L2-hot after k_prep)
    short8 bfr[8][2];
    #pragma unroll
    for (int kb = 0; kb < 8; ++kb)
        #pragma unroll
        for (int nf = 0; nf < 2; ++nf)
            bfr[kb][nf] = *(const short8*)&w1b[(size_t)(hb + nf * 16 + l15) * HD + kb * 32 + lk * 8];

    // per-lane g23/W4 for C rows h = hb + nf*16 + lk*4 + r
    float gv[2][4], wv[2][4];
    #pragma unroll
    for (int nf = 0; nf < 2; ++nf)
        #pragma unroll
        for (int r = 0; r < 4; ++r) {
            int h = hb + nf * 16 + lk * 4 + r;
            gv[nf][r] = g23[b * HD + h];
            wv[nf][r] = W4[h];
        }

    float* cur = buf0;
    float* nxt = buf1;

    #pragma unroll 1
    for (int st = 0; st < NT; ++st) {
        SYNC_LDS();                      // B1: all waves done reading nxt (prev iter)
        if (st + 1 < NT) {
            stage32(qc + (size_t)(st + 1) * 32 * HD, nxt, wave, lane);
            WAITV4();                    // drain cur's 4 loads; nxt's 4 stay in flight
        } else {
            WAITV0();
        }
        BARRIER();                       // B2: cur fully staged by all waves

        // passA: C[h][d] for d in {l15, 16+l15}; f32 frags cvt'd in-flight
        float s0, s1;
        #pragma unroll
        for (int mf = 0; mf < 2; ++mf) {
            float4v a0 = {0.f, 0.f, 0.f, 0.f}, a1 = {0.f, 0.f, 0.f, 0.f};
            const int d = mf * 16 + l15;
            const int dsw = d & 7;
            #pragma unroll
            for (int kb = 0; kb < 8; ++kb) {
                int g = kb * 4 + lk;                       // 32B k-granule
                int byte = d * 1024 + ((g ^ dsw) << 5);
                float4v lo = *(const float4v*)((const char*)cur + byte);
                float4v hi = *(const float4v*)((const char*)cur + byte + 16);
                short8 bq = cvt8(lo, hi);
                a0 = __builtin_amdgcn_mfma_f32_16x16x32_bf16(bfr[kb][0], bq, a0, 0, 0, 0);
                a1 = __builtin_amdgcn_mfma_f32_16x16x32_bf16(bfr[kb][1], bq, a1, 0, 0, 0);
            }
            float s = 0.f;
            #pragma unroll
            for (int r = 0; r < 4; ++r) s += fast_tanh(a0[r] + gv[0][r]) * wv[0][r];
            #pragma unroll
            for (int r = 0; r < 4; ++r) s += fast_tanh(a1[r] + gv[1][r]) * wv[1][r];
            s += __shfl_xor(s, 16, 64);
            s += __shfl_xor(s, 32, 64);
            if (mf == 0) s0 = s; else s1 = s;
        }
        // wave-private row: no cross-wave sync, no passB
        float sv = (lane < 16) ? s0 : s1;
        if (lane < 32) sp_acc[wave][st * 32 + lane] = sv;

        float* tmp = cur; cur = nxt; nxt = tmp;
    }

    // single cross-wave reduction at kernel end
    SYNC_LDS();
    if (t < HD) {
        float s = sp_acc[0][t] + sp_acc[1][t] + sp_acc[2][t] + sp_acc[3][t]
                + sp_acc[4][t] + sp_acc[5][t] + sp_acc[6][t] + sp_acc[7][t];
        scores[b * DD + chunk * 256 + t] = s;   // b4 dropped (softmax shift-inv)
    }
}

// ---------------- kernel 2: per-batch softmax stats ----------------
__global__ __launch_bounds__(256) void k_stats(const float* __restrict__ scores,
                                               float* __restrict__ stats) {
    int b = blockIdx.x, t = threadIdx.x;
    __shared__ float red[256];
    float sv[8];
    float lm = -1e30f;
    #pragma unroll
    for (int i = 0; i < 8; ++i) {
        sv[i] = scores[b * DD + t + i * 256];
        lm = fmaxf(lm, sv[i]);
    }
    red[t] = lm; __syncthreads();
    for (int s = 128; s > 0; s >>= 1) {
        if (t < s) red[t] = fmaxf(red[t], red[t + s]);
        __syncthreads();
    }
    float mx = red[0];
    __syncthreads();
    float ls = 0.f;
    #pragma unroll
    for (int i = 0; i < 8; ++i) ls += fast_expf(sv[i] - mx);
    red[t] = ls; __syncthreads();
    for (int s = 128; s > 0; s >>= 1) {
        if (t < s) red[t] += red[t + s];
        __syncthreads();
    }
    if (t == 0) { stats[b * 2] = mx; stats[b * 2 + 1] = 1.f / red[0]; }
}

// ---------------- kernel 3: partial weighted sums (L3-hot second q pass) -------
__global__ __launch_bounds__(256) void k_pout(const float* __restrict__ q,
                                              const float* __restrict__ scores,
                                              const float* __restrict__ stats,
                                              float* __restrict__ part) {
    const int b = blockIdx.y, ch = blockIdx.x, t = threadIdx.x;
    __shared__ float wl[256];
    __shared__ float4v red[256];
    const float mx = stats[b * 2], inv = stats[b * 2 + 1];
    const int d0 = ch * 256;
    wl[t] = fast_expf(scores[b * DD + d0 + t] - mx) * inv;
    __syncthreads();
    const int rg = t >> 6, cg = t & 63;       // row-group, col-float4
    const float4v* qb = (const float4v*)(q + ((size_t)(b * DD + d0 + rg)) * HD) + cg;
    float4v a0 = {0,0,0,0}, a1 = {0,0,0,0};
    #pragma unroll 8
    for (int i = 0; i < 64; i += 2) {
        a0 += qb[(size_t)i * 256]       * wl[rg + i * 4];
        a1 += qb[(size_t)(i + 1) * 256] * wl[rg + (i + 1) * 4];
    }
    red[t] = a0 + a1;
    __syncthreads();
    if (t < 64) {
        float4v s = red[t] + red[t + 64] + red[t + 128] + red[t + 192];
        ((float4v*)part)[((size_t)(b * 8 + ch)) * 64 + t] = s;
    }
}

// ---------------- kernel 4: reduce partials ----------------
__global__ __launch_bounds__(64) void k_rout(const float* __restrict__ part,
                                             float* __restrict__ out) {
    int b = blockIdx.x, t = threadIdx.x;
    float4v s = {0,0,0,0};
    #pragma unroll
    for (int c = 0; c < 8; ++c) s += ((const float4v*)part)[((size_t)(b * 8 + c)) * 64 + t];
    ((float4v*)out)[b * 64 + t] = s;
}

extern "C" void kernel_launch(void* const* d_in, const int* in_sizes, int n_in,
                              void* d_out, int out_size, void* d_ws, size_t ws_size,
                              hipStream_t stream) {
    (void)in_sizes; (void)n_in; (void)out_size; (void)ws_size;
    const float* ctx = (const float*)d_in[0];
    const float* q   = (const float*)d_in[1];
    const float* hid = (const float*)d_in[2];
    const float* W1  = (const float*)d_in[3];
    const float* W2  = (const float*)d_in[4];
    const float* b2  = (const float*)d_in[5];
    const float* W3  = (const float*)d_in[6];
    const float* W4  = (const float*)d_in[7];
    // d_in[8] = b4: dropped (softmax shift-invariant)
    float* out = (float*)d_out;

    char* ws = (char*)d_ws;
    unsigned short* w1b = (unsigned short*)(ws);            // 131072 B
    float* g23    = (float*)(ws + 131072);                  //  65536 B
    float* scores = (float*)(ws + 196608);                  // 524288 B
    float* stats  = (float*)(ws + 720896);                  //    512 B
    float* part   = (float*)(ws + 721408);                  // 524288 B

    k_prep  <<<dim3(128), dim3(256), 0, stream>>>(W1, w1b, ctx, hid, W2, b2, W3, g23);
    k_scores<<<dim3(NCHK, BB), dim3(512), 0, stream>>>(q, w1b, g23, W4, scores);
    k_stats <<<dim3(BB), dim3(256), 0, stream>>>(scores, stats);
    k_pout  <<<dim3(8, BB), dim3(256), 0, stream>>>(q, scores, stats, part);
    k_rout  <<<dim3(BB), dim3(64), 0, stream>>>(part, out);
}

// Round 13
// 83.919 us; speedup vs baseline: 1.9952x; 1.0644x over previous
//
#include <hip/hip_runtime.h>
#include <hip/hip_bf16.h>
#include <math.h>

#define HD 256
#define BB 64
#define DD 2048
#define NQ 4            // 512-row chunks per batch
#define NST 8           // 64-row sub-tiles per chunk

typedef __attribute__((ext_vector_type(8))) short  short8;
typedef __attribute__((ext_vector_type(4))) float  float4v;
typedef __attribute__((ext_vector_type(4))) unsigned uint4v;
typedef __attribute__((ext_vector_type(4))) unsigned short ushort4v;

__device__ inline unsigned short f2bf(float f) {
    unsigned u = __builtin_bit_cast(unsigned, f);
    u += 0x7FFFu + ((u >> 16) & 1u);   // RNE
    return (unsigned short)(u >> 16);
}

__device__ inline unsigned cvt_pk_bf16(float lo, float hi) {
    unsigned r;
    asm("v_cvt_pk_bf16_f32 %0, %1, %2" : "=v"(r) : "v"(lo), "v"(hi));
    return r;
}
__device__ inline short8 cvt8(float4v lo, float4v hi) {
    uint4v u;
    u[0] = cvt_pk_bf16(lo[0], lo[1]);
    u[1] = cvt_pk_bf16(lo[2], lo[3]);
    u[2] = cvt_pk_bf16(hi[0], hi[1]);
    u[3] = cvt_pk_bf16(hi[2], hi[3]);
    return __builtin_bit_cast(short8, u);
}

__device__ inline float fast_exp2(float x) {
    float r;
    asm("v_exp_f32 %0, %1" : "=v"(r) : "v"(x));
    return r;
}
__device__ inline float fast_expf(float x) { return fast_exp2(x * 1.4426950408889634f); }
__device__ inline float fast_tanh(float x) {
    float y = x * 2.8853900817779268f;          // 2x * log2(e)
    y = fminf(fmaxf(y, -30.f), 30.f);
    float t = fast_exp2(y);
    float r;
    asm("v_rcp_f32 %0, %1" : "=v"(r) : "v"(t + 1.f));
    return (t - 1.f) * r;
}

// LDS-only barrier: orders LDS traffic without draining vmcnt.
#define SYNC_LDS() do { asm volatile("s_waitcnt lgkmcnt(0)" ::: "memory"); \
                        __builtin_amdgcn_s_barrier(); \
                        asm volatile("" ::: "memory"); } while (0)
#define WAITV8()  asm volatile("s_waitcnt vmcnt(8)" ::: "memory")
#define WAITV0()  asm volatile("s_waitcnt vmcnt(0)" ::: "memory")
#define BARRIER() do { __builtin_amdgcn_s_barrier(); asm volatile("" ::: "memory"); } while (0)

__device__ inline void load_lds16(const void* g, void* l) {
    __builtin_amdgcn_global_load_lds(
        (const __attribute__((address_space(1))) void*)g,
        (__attribute__((address_space(3))) void*)l, 16, 0, 0);
}

// stage one 64-row f32 sub-tile; wave stages rows [wave*8, wave*8+8).
// Source pre-swizzled on 32B granules (g ^= r&7); LDS dest linear (rule 21).
__device__ inline void stage(const float* qtile, float* buf, int wave, int lane) {
    const int half = lane & 1;
    #pragma unroll
    for (int i = 0; i < 8; ++i) {
        int r = wave * 8 + i;
        int gsrc = ((((lane >> 1) ^ (r & 7)) << 1) | half) << 4;   // byte in row
        load_lds16((const char*)qtile + (size_t)r * 1024 + gsrc,
                   (char*)buf + r * 1024);
    }
}

// ---------------- kernel 0 (fused prep): W1 f32->bf16  AND  g23 ----------------
__global__ __launch_bounds__(256) void k_prep(const float* __restrict__ W1,
                                              unsigned short* __restrict__ w1b,
                                              const float* __restrict__ ctx,
                                              const float* __restrict__ hid,
                                              const float* __restrict__ W2,
                                              const float* __restrict__ b2,
                                              const float* __restrict__ W3,
                                              float* __restrict__ g23) {
    if (blockIdx.x < 64) {
        int i = blockIdx.x * 256 + threadIdx.x;
        float4v v = ((const float4v*)W1)[i];
        ushort4v o;
        o[0] = f2bf(v[0]); o[1] = f2bf(v[1]); o[2] = f2bf(v[2]); o[3] = f2bf(v[3]);
        ((ushort4v*)w1b)[i] = o;
    } else {
        int b = blockIdx.x - 64, t = threadIdx.x;
        __shared__ float c[HD], hh[HD];
        c[t]  = ctx[b * HD + t];
        hh[t] = hid[b * HD + t];
        __syncthreads();
        const float4v* w2 = (const float4v*)(W2 + (size_t)t * HD);
        const float4v* w3 = (const float4v*)(W3 + (size_t)t * HD);
        float acc = b2[t];
        #pragma unroll 8
        for (int k = 0; k < 64; ++k) {
            float4v a = w2[k], d = w3[k];
            int k4 = k * 4;
            acc += c[k4] * a[0] + c[k4 + 1] * a[1] + c[k4 + 2] * a[2] + c[k4 + 3] * a[3];
            acc += hh[k4] * d[0] + hh[k4 + 1] * d[1] + hh[k4 + 2] * d[2] + hh[k4 + 3] * d[3];
        }
        g23[b * HD + t] = acc;
    }
}

// ---------------- kernel 1: scores = W4 . tanh(q@W1^T + g23) -------------------
// grid (4, 64) = 256 blocks = 1/CU. 512 thr, 8 waves. Wave w = (hg=w>>1, dh=w&1):
// owns 64 h (bfr = 128 VGPR) and reads ONLY its 32-row half of each 64-row
// sub-tile (2x less redundant B-fragment DS traffic than r8). r8 skeleton:
// gload_lds f32 staging, counted vmcnt(8), 2 LDS-only barriers per sub-tile;
// wave-private sp_acc rows, single 4-way h-group sum at kernel end.
__global__ __launch_bounds__(512) void k_scores(const float* __restrict__ q,
                                                const unsigned short* __restrict__ w1b,
                                                const float* __restrict__ g23,
                                                const float* __restrict__ W4,
                                                float* __restrict__ scores) {
    __shared__ __attribute__((aligned(16))) float buf0[64 * HD];   // 64 KB
    __shared__ __attribute__((aligned(16))) float buf1[64 * HD];   // 64 KB
    __shared__ float sp_acc[8][NST * 32];                          // 8 KB

    const int t = threadIdx.x;
    const int chunk = blockIdx.x, b = blockIdx.y;
    const int lane = t & 63, wave = t >> 6;
    const int l15 = lane & 15, lk = lane >> 4;
    const int hg = wave >> 1, dh = wave & 1;
    const int hb = hg * 64;

    const float* qc = q + ((size_t)b * DD + chunk * 512) * HD;

    // issue sub-tile 0 immediately
    stage(qc, buf0, wave, lane);

    // W1 slice (A operand, 64 h) -> 128 VGPR (L2-hot after k_prep)
    short8 bfr[8][4];
    #pragma unroll
    for (int kb = 0; kb < 8; ++kb)
        #pragma unroll
        for (int nf = 0; nf < 4; ++nf)
            bfr[kb][nf] = *(const short8*)&w1b[(size_t)(hb + nf * 16 + l15) * HD + kb * 32 + lk * 8];

    // per-lane g23/W4 for C rows h = hb + nf*16 + lk*4 + r
    float gv[4][4], wv[4][4];
    #pragma unroll
    for (int nf = 0; nf < 4; ++nf)
        #pragma unroll
        for (int r = 0; r < 4; ++r) {
            int h = hb + nf * 16 + lk * 4 + r;
            gv[nf][r] = g23[b * HD + h];
            wv[nf][r] = W4[h];
        }

    float* cur = buf0;
    float* nxt = buf1;

    #pragma unroll 1
    for (int st = 0; st < NST; ++st) {
        SYNC_LDS();                      // B1: all waves done reading nxt (prev iter)
        if (st + 1 < NST) {
            stage(qc + (size_t)(st + 1) * 64 * HD, nxt, wave, lane);
            WAITV8();                    // drain cur's 8 loads; nxt's 8 stay in flight
        } else {
            WAITV0();
        }
        BARRIER();                       // B2: cur fully staged by all waves

        // passA: C[64 h][this wave's 32 rows], f32 frags cvt'd in-flight
        float s0, s1;
        #pragma unroll
        for (int mf = 0; mf < 2; ++mf) {
            float4v a0 = {0.f,0.f,0.f,0.f}, a1 = {0.f,0.f,0.f,0.f};
            float4v a2 = {0.f,0.f,0.f,0.f}, a3 = {0.f,0.f,0.f,0.f};
            const int d = dh * 32 + mf * 16 + l15;     // row in 64-row tile
            const int dsw = d & 7;
            #pragma unroll
            for (int kb = 0; kb < 8; ++kb) {
                int g = kb * 4 + lk;                   // 32B k-granule
                int byte = d * 1024 + ((g ^ dsw) << 5);
                float4v lo = *(const float4v*)((const char*)cur + byte);
                float4v hi = *(const float4v*)((const char*)cur + byte + 16);
                short8 bq = cvt8(lo, hi);
                a0 = __builtin_amdgcn_mfma_f32_16x16x32_bf16(bfr[kb][0], bq, a0, 0, 0, 0);
                a1 = __builtin_amdgcn_mfma_f32_16x16x32_bf16(bfr[kb][1], bq, a1, 0, 0, 0);
                a2 = __builtin_amdgcn_mfma_f32_16x16x32_bf16(bfr[kb][2], bq, a2, 0, 0, 0);
                a3 = __builtin_amdgcn_mfma_f32_16x16x32_bf16(bfr[kb][3], bq, a3, 0, 0, 0);
            }
            float s = 0.f;
            #pragma unroll
            for (int r = 0; r < 4; ++r) s += fast_tanh(a0[r] + gv[0][r]) * wv[0][r];
            #pragma unroll
            for (int r = 0; r < 4; ++r) s += fast_tanh(a1[r] + gv[1][r]) * wv[1][r];
            #pragma unroll
            for (int r = 0; r < 4; ++r) s += fast_tanh(a2[r] + gv[2][r]) * wv[2][r];
            #pragma unroll
            for (int r = 0; r < 4; ++r) s += fast_tanh(a3[r] + gv[3][r]) * wv[3][r];
            s += __shfl_xor(s, 16, 64);
            s += __shfl_xor(s, 32, 64);
            if (mf == 0) s0 = s; else s1 = s;
        }
        // wave-private row (this wave's 32 rows of the sub-tile): no cross-wave sync
        float sv = (lane < 16) ? s0 : s1;
        if (lane < 32) sp_acc[wave][st * 32 + lane] = sv;

        float* tmp = cur; cur = nxt; nxt = tmp;
    }

    // end: sum the 4 h-group partials for each of the 512 rows
    SYNC_LDS();
    {
        int x = t;                        // 512 rows
        int st = x >> 6, xx = x & 63;
        int dh2 = xx >> 5, rr = xx & 31;
        int idx = st * 32 + rr;
        float s = sp_acc[dh2][idx] + sp_acc[2 + dh2][idx]
                + sp_acc[4 + dh2][idx] + sp_acc[6 + dh2][idx];
        scores[b * DD + chunk * 512 + x] = s;   // b4 dropped (softmax shift-inv)
    }
}

// ---------------- kernel 2: per-batch softmax stats ----------------
__global__ __launch_bounds__(256) void k_stats(const float* __restrict__ scores,
                                               float* __restrict__ stats) {
    int b = blockIdx.x, t = threadIdx.x;
    __shared__ float red[256];
    float sv[8];
    float lm = -1e30f;
    #pragma unroll
    for (int i = 0; i < 8; ++i) {
        sv[i] = scores[b * DD + t + i * 256];
        lm = fmaxf(lm, sv[i]);
    }
    red[t] = lm; __syncthreads();
    for (int s = 128; s > 0; s >>= 1) {
        if (t < s) red[t] = fmaxf(red[t], red[t + s]);
        __syncthreads();
    }
    float mx = red[0];
    __syncthreads();
    float ls = 0.f;
    #pragma unroll
    for (int i = 0; i < 8; ++i) ls += fast_expf(sv[i] - mx);
    red[t] = ls; __syncthreads();
    for (int s = 128; s > 0; s >>= 1) {
        if (t < s) red[t] += red[t + s];
        __syncthreads();
    }
    if (t == 0) { stats[b * 2] = mx; stats[b * 2 + 1] = 1.f / red[0]; }
}

// ---------------- kernel 3: partial weighted sums (L3-hot second q pass) -------
__global__ __launch_bounds__(256) void k_pout(const float* __restrict__ q,
                                              const float* __restrict__ scores,
                                              const float* __restrict__ stats,
                                              float* __restrict__ part) {
    const int b = blockIdx.y, ch = blockIdx.x, t = threadIdx.x;
    __shared__ float wl[256];
    __shared__ float4v red[256];
    const float mx = stats[b * 2], inv = stats[b * 2 + 1];
    const int d0 = ch * 256;
    wl[t] = fast_expf(scores[b * DD + d0 + t] - mx) * inv;
    __syncthreads();
    const int rg = t >> 6, cg = t & 63;       // row-group, col-float4
    const float4v* qb = (const float4v*)(q + ((size_t)(b * DD + d0 + rg)) * HD) + cg;
    float4v a0 = {0,0,0,0}, a1 = {0,0,0,0};
    #pragma unroll 8
    for (int i = 0; i < 64; i += 2) {
        a0 += qb[(size_t)i * 256]       * wl[rg + i * 4];
        a1 += qb[(size_t)(i + 1) * 256] * wl[rg + (i + 1) * 4];
    }
    red[t] = a0 + a1;
    __syncthreads();
    if (t < 64) {
        float4v s = red[t] + red[t + 64] + red[t + 128] + red[t + 192];
        ((float4v*)part)[((size_t)(b * 8 + ch)) * 64 + t] = s;
    }
}

// ---------------- kernel 4: reduce partials ----------------
__global__ __launch_bounds__(64) void k_rout(const float* __restrict__ part,
                                             float* __restrict__ out) {
    int b = blockIdx.x, t = threadIdx.x;
    float4v s = {0,0,0,0};
    #pragma unroll
    for (int c = 0; c < 8; ++c) s += ((const float4v*)part)[((size_t)(b * 8 + c)) * 64 + t];
    ((float4v*)out)[b * 64 + t] = s;
}

extern "C" void kernel_launch(void* const* d_in, const int* in_sizes, int n_in,
                              void* d_out, int out_size, void* d_ws, size_t ws_size,
                              hipStream_t stream) {
    (void)in_sizes; (void)n_in; (void)out_size; (void)ws_size;
    const float* ctx = (const float*)d_in[0];
    const float* q   = (const float*)d_in[1];
    const float* hid = (const float*)d_in[2];
    const float* W1  = (const float*)d_in[3];
    const float* W2  = (const float*)d_in[4];
    const float* b2  = (const float*)d_in[5];
    const float* W3  = (const float*)d_in[6];
    const float* W4  = (const float*)d_in[7];
    // d_in[8] = b4: dropped (softmax shift-invariant)
    float* out = (float*)d_out;

    char* ws = (char*)d_ws;
    unsigned short* w1b = (unsigned short*)(ws);            // 131072 B
    float* g23    = (float*)(ws + 131072);                  //  65536 B
    float* scores = (float*)(ws + 196608);                  // 524288 B
    float* stats  = (float*)(ws + 720896);                  //    512 B
    float* part   = (float*)(ws + 721408);                  // 524288 B

    k_prep  <<<dim3(128), dim3(256), 0, stream>>>(W1, w1b, ctx, hid, W2, b2, W3, g23);
    k_scores<<<dim3(NQ, BB), dim3(512), 0, stream>>>(q, w1b, g23, W4, scores);
    k_stats <<<dim3(BB), dim3(256), 0, stream>>>(scores, stats);
    k_pout  <<<dim3(8, BB), dim3(256), 0, stream>>>(q, scores, stats, part);
    k_rout  <<<dim3(BB), dim3(64), 0, stream>>>(part, out);
}

// Round 14
// 76.858 us; speedup vs baseline: 2.1785x; 1.0919x over previous
//
#include <hip/hip_runtime.h>
#include <hip/hip_bf16.h>
#include <math.h>

#define HD 256
#define BB 64
#define DD 2048
#define NQ 4            // 512-row chunks per batch
#define NST 8           // 64-row sub-tiles per chunk

typedef __attribute__((ext_vector_type(8))) short  short8;
typedef __attribute__((ext_vector_type(4))) float  float4v;
typedef __attribute__((ext_vector_type(4))) unsigned uint4v;
typedef __attribute__((ext_vector_type(4))) unsigned short ushort4v;

__device__ inline unsigned short f2bf(float f) {
    unsigned u = __builtin_bit_cast(unsigned, f);
    u += 0x7FFFu + ((u >> 16) & 1u);   // RNE
    return (unsigned short)(u >> 16);
}

__device__ inline float fast_exp2(float x) {
    float r;
    asm("v_exp_f32 %0, %1" : "=v"(r) : "v"(x));
    return r;
}
__device__ inline float fast_expf(float x) { return fast_exp2(x * 1.4426950408889634f); }
__device__ inline float fast_tanh(float x) {
    float y = x * 2.8853900817779268f;          // 2x * log2(e)
    y = fminf(fmaxf(y, -30.f), 30.f);
    float t = fast_exp2(y);
    float r;
    asm("v_rcp_f32 %0, %1" : "=v"(r) : "v"(t + 1.f));
    return (t - 1.f) * r;
}

// LDS-only barrier: orders LDS traffic without draining vmcnt.
#define SYNC_LDS() do { asm volatile("s_waitcnt lgkmcnt(0)" ::: "memory"); \
                        __builtin_amdgcn_s_barrier(); \
                        asm volatile("" ::: "memory"); } while (0)
#define WAITV8()  asm volatile("s_waitcnt vmcnt(8)" ::: "memory")
#define WAITV0()  asm volatile("s_waitcnt vmcnt(0)" ::: "memory")
#define BARRIER() do { __builtin_amdgcn_s_barrier(); asm volatile("" ::: "memory"); } while (0)

__device__ inline void load_lds16(const void* g, void* l) {
    __builtin_amdgcn_global_load_lds(
        (const __attribute__((address_space(1))) void*)g,
        (__attribute__((address_space(3))) void*)l, 16, 0, 0);
}

// stage one 64-row f32 sub-tile; wave stages rows [wave*8, wave*8+8).
// Source pre-swizzled on 32B granules (g ^= r&7); LDS dest linear (rule 21).
__device__ inline void stage(const float* qtile, float* buf, int wave, int lane) {
    const int half = lane & 1;
    #pragma unroll
    for (int i = 0; i < 8; ++i) {
        int r = wave * 8 + i;
        int gsrc = ((((lane >> 1) ^ (r & 7)) << 1) | half) << 4;   // byte in row
        load_lds16((const char*)qtile + (size_t)r * 1024 + gsrc,
                   (char*)buf + r * 1024);
    }
}

// ---------------- kernel 0 (fused prep): W1 f32->bf16  AND  g23 ----------------
__global__ __launch_bounds__(256) void k_prep(const float* __restrict__ W1,
                                              unsigned short* __restrict__ w1b,
                                              const float* __restrict__ ctx,
                                              const float* __restrict__ hid,
                                              const float* __restrict__ W2,
                                              const float* __restrict__ b2,
                                              const float* __restrict__ W3,
                                              float* __restrict__ g23) {
    if (blockIdx.x < 64) {
        int i = blockIdx.x * 256 + threadIdx.x;
        float4v v = ((const float4v*)W1)[i];
        ushort4v o;
        o[0] = f2bf(v[0]); o[1] = f2bf(v[1]); o[2] = f2bf(v[2]); o[3] = f2bf(v[3]);
        ((ushort4v*)w1b)[i] = o;
    } else {
        int b = blockIdx.x - 64, t = threadIdx.x;
        __shared__ float c[HD], hh[HD];
        c[t]  = ctx[b * HD + t];
        hh[t] = hid[b * HD + t];
        __syncthreads();
        const float4v* w2 = (const float4v*)(W2 + (size_t)t * HD);
        const float4v* w3 = (const float4v*)(W3 + (size_t)t * HD);
        float acc = b2[t];
        #pragma unroll 8
        for (int k = 0; k < 64; ++k) {
            float4v a = w2[k], d = w3[k];
            int k4 = k * 4;
            acc += c[k4] * a[0] + c[k4 + 1] * a[1] + c[k4 + 2] * a[2] + c[k4 + 3] * a[3];
            acc += hh[k4] * d[0] + hh[k4 + 1] * d[1] + hh[k4 + 2] * d[2] + hh[k4 + 3] * d[3];
        }
        g23[b * HD + t] = acc;
    }
}

// ---------------- kernel 1: fused scores + bounded-exp softmax + PV ------------
// grid (4, 64) = 256 blocks = 1/CU. 512 thr, 8 waves; wave (hg=w>>1, dh=w&1):
// owns 64 h (bfr = 128 VGPR), reads only its 32-row half (r13 split).
// |scores| <= sum|W4| ~ 16 (tanh bounded) => exp without max subtraction is
// fp32-safe: NO stat shfl chains, NO online rescale. r8 skeleton otherwise:
// gload_lds f32, counted vmcnt(8), LDS-only barriers, in-kernel PV.
__global__ __launch_bounds__(512) void k_fused(const float* __restrict__ q,
                                               const unsigned short* __restrict__ w1b,
                                               const float* __restrict__ g23,
                                               const float* __restrict__ W4,
                                               float* __restrict__ pl,
                                               float* __restrict__ pO) {
    __shared__ __attribute__((aligned(16))) float buf0[64 * HD];   // 64 KB
    __shared__ __attribute__((aligned(16))) float buf1[64 * HD];   // 64 KB
    __shared__ float sp_t[4][64];                                  // partials by hg

    const int t = threadIdx.x;
    const int chunk = blockIdx.x, b = blockIdx.y;
    const int lane = t & 63, wave = t >> 6;
    const int l15 = lane & 15, lk = lane >> 4;
    const int hg = wave >> 1, dh = wave & 1;
    const int hb = hg * 64;
    const int cq = lane & 7, ro = lane >> 3;   // PV: col-quad, row-oct

    const float* qc = q + ((size_t)b * DD + chunk * 512) * HD;

    // issue sub-tile 0 immediately
    stage(qc, buf0, wave, lane);

    // W1 slice (A operand, 64 h) -> 128 VGPR (L2-hot after k_prep)
    short8 bfr[8][4];
    #pragma unroll
    for (int kb = 0; kb < 8; ++kb)
        #pragma unroll
        for (int nf = 0; nf < 4; ++nf)
            bfr[kb][nf] = *(const short8*)&w1b[(size_t)(hb + nf * 16 + l15) * HD + kb * 32 + lk * 8];

    // per-lane g23/W4 for C rows h = hb + nf*16 + lk*4 + r
    float gv[4][4], wv[4][4];
    #pragma unroll
    for (int nf = 0; nf < 4; ++nf)
        #pragma unroll
        for (int r = 0; r < 4; ++r) {
            int h = hb + nf * 16 + lk * 4 + r;
            gv[nf][r] = g23[b * HD + h];
            wv[nf][r] = W4[h];
        }

    float l = 0.f;
    float4v O = {0.f, 0.f, 0.f, 0.f};
    float* cur = buf0;
    float* nxt = buf1;

    #pragma unroll 1
    for (int st = 0; st < NST; ++st) {
        SYNC_LDS();                      // B1: all waves done reading nxt (prev iter)
        if (st + 1 < NST) {
            stage(qc + (size_t)(st + 1) * 64 * HD, nxt, wave, lane);
            WAITV8();                    // drain cur's 8 loads; nxt's 8 stay in flight
        } else {
            WAITV0();
        }
        BARRIER();                       // B2: cur fully staged by all waves

        // passA: C[64 h][this wave's 32 rows]; f32 frags cvt'd in-flight
        float s0, s1;
        #pragma unroll
        for (int mf = 0; mf < 2; ++mf) {
            float4v a0 = {0.f,0.f,0.f,0.f}, a1 = {0.f,0.f,0.f,0.f};
            float4v a2 = {0.f,0.f,0.f,0.f}, a3 = {0.f,0.f,0.f,0.f};
            const int d = dh * 32 + mf * 16 + l15;     // row in 64-row tile
            const int dsw = d & 7;
            #pragma unroll
            for (int kb = 0; kb < 8; ++kb) {
                int g = kb * 4 + lk;                   // 32B k-granule
                int byte = d * 1024 + ((g ^ dsw) << 5);
                float4v lo = *(const float4v*)((const char*)cur + byte);
                float4v hi = *(const float4v*)((const char*)cur + byte + 16);
                short8 bq;
                {
                    uint4v u;
                    asm("v_cvt_pk_bf16_f32 %0, %1, %2" : "=v"(u[0]) : "v"(lo[0]), "v"(lo[1]));
                    asm("v_cvt_pk_bf16_f32 %0, %1, %2" : "=v"(u[1]) : "v"(lo[2]), "v"(lo[3]));
                    asm("v_cvt_pk_bf16_f32 %0, %1, %2" : "=v"(u[2]) : "v"(hi[0]), "v"(hi[1]));
                    asm("v_cvt_pk_bf16_f32 %0, %1, %2" : "=v"(u[3]) : "v"(hi[2]), "v"(hi[3]));
                    bq = __builtin_bit_cast(short8, u);
                }
                a0 = __builtin_amdgcn_mfma_f32_16x16x32_bf16(bfr[kb][0], bq, a0, 0, 0, 0);
                a1 = __builtin_amdgcn_mfma_f32_16x16x32_bf16(bfr[kb][1], bq, a1, 0, 0, 0);
                a2 = __builtin_amdgcn_mfma_f32_16x16x32_bf16(bfr[kb][2], bq, a2, 0, 0, 0);
                a3 = __builtin_amdgcn_mfma_f32_16x16x32_bf16(bfr[kb][3], bq, a3, 0, 0, 0);
            }
            float s = 0.f;
            #pragma unroll
            for (int r = 0; r < 4; ++r) s += fast_tanh(a0[r] + gv[0][r]) * wv[0][r];
            #pragma unroll
            for (int r = 0; r < 4; ++r) s += fast_tanh(a1[r] + gv[1][r]) * wv[1][r];
            #pragma unroll
            for (int r = 0; r < 4; ++r) s += fast_tanh(a2[r] + gv[2][r]) * wv[2][r];
            #pragma unroll
            for (int r = 0; r < 4; ++r) s += fast_tanh(a3[r] + gv[3][r]) * wv[3][r];
            s += __shfl_xor(s, 16, 64);
            s += __shfl_xor(s, 32, 64);
            if (mf == 0) s0 = s; else s1 = s;
        }
        // partial over this wave's 64 h for its 32 rows -> sp_t[hg][row]
        float sv = (lane < 16) ? s0 : s1;
        if (lane < 32) sp_t[hg][dh * 32 + lane] = sv;
        SYNC_LDS();                      // B3: sp_t published

        // passB: bounded exp (no max chains, no rescale) + PV
        float sc = sp_t[0][lane] + sp_t[1][lane] + sp_t[2][lane] + sp_t[3][lane];
        float w = fast_exp2(sc * 1.4426950408889634f);
        l += w;                          // lane's row = lane; redundant per wave
        const int gq = wave * 4 + (cq >> 1);
        const int hoff = (cq & 1) << 4;
        #pragma unroll
        for (int i = 0; i < 8; ++i) {
            int d = ro * 8 + i;
            float wd = __shfl(w, d, 64);
            int byte = d * 1024 + ((gq ^ (d & 7)) << 5) + hoff;
            float4v v = *(const float4v*)((const char*)cur + byte);
            O += wd * v;
        }

        float* tmp = cur; cur = nxt; nxt = tmp;
    }

    // reduce O over the 8 row-octs (lanes sharing cq)
    #pragma unroll
    for (int j = 0; j < 4; ++j) {
        O[j] += __shfl_xor(O[j], 8, 64);
        O[j] += __shfl_xor(O[j], 16, 64);
        O[j] += __shfl_xor(O[j], 32, 64);
    }
    if (ro == 0)
        *(float4v*)&pO[((size_t)(b * NQ + chunk)) * HD + wave * 32 + cq * 4] = O;

    // reduce l over 64 lanes (identical across waves); one write
    l += __shfl_xor(l, 1, 64);
    l += __shfl_xor(l, 2, 64);
    l += __shfl_xor(l, 4, 64);
    l += __shfl_xor(l, 8, 64);
    l += __shfl_xor(l, 16, 64);
    l += __shfl_xor(l, 32, 64);
    if (t == 0) pl[b * NQ + chunk] = l;
}

// ---------------- kernel 2: combine 4 chunk-partials per batch -----------------
__global__ __launch_bounds__(256) void k_comb(const float* __restrict__ pl,
                                              const float* __restrict__ pO,
                                              float* __restrict__ out) {
    int b = blockIdx.x, t = threadIdx.x;
    float L = pl[b * NQ] + pl[b * NQ + 1] + pl[b * NQ + 2] + pl[b * NQ + 3];
    float s = 0.f;
    #pragma unroll
    for (int c = 0; c < NQ; ++c) s += pO[((size_t)(b * NQ + c)) * HD + t];
    out[b * HD + t] = s / L;
}

extern "C" void kernel_launch(void* const* d_in, const int* in_sizes, int n_in,
                              void* d_out, int out_size, void* d_ws, size_t ws_size,
                              hipStream_t stream) {
    (void)in_sizes; (void)n_in; (void)out_size; (void)ws_size;
    const float* ctx = (const float*)d_in[0];
    const float* q   = (const float*)d_in[1];
    const float* hid = (const float*)d_in[2];
    const float* W1  = (const float*)d_in[3];
    const float* W2  = (const float*)d_in[4];
    const float* b2  = (const float*)d_in[5];
    const float* W3  = (const float*)d_in[6];
    const float* W4  = (const float*)d_in[7];
    // d_in[8] = b4: cancels exactly in exp-sum ratio (softmax shift-invariance)
    float* out = (float*)d_out;

    char* ws = (char*)d_ws;
    unsigned short* w1b = (unsigned short*)(ws);            // 131072 B
    float* g23 = (float*)(ws + 131072);                     //  65536 B
    float* pl  = (float*)(ws + 196608);                     //   1024 B
    float* pO  = (float*)(ws + 197632);                     // 262144 B

    k_prep <<<dim3(128), dim3(256), 0, stream>>>(W1, w1b, ctx, hid, W2, b2, W3, g23);
    k_fused<<<dim3(NQ, BB), dim3(512), 0, stream>>>(q, w1b, g23, W4, pl, pO);
    k_comb <<<dim3(BB), dim3(256), 0, stream>>>(pl, pO, out);
}

// Round 15
// 68.206 us; speedup vs baseline: 2.4548x; 1.1268x over previous
//
#include <hip/hip_runtime.h>
#include <hip/hip_bf16.h>
#include <math.h>

#define HD 256
#define BB 64
#define DD 2048
#define NQ 4            // quarters per batch (512 rows each)
#define NST 8           // 64-row sub-tiles per quarter

typedef __attribute__((ext_vector_type(8))) short  short8;
typedef __attribute__((ext_vector_type(4))) float  float4v;
typedef __attribute__((ext_vector_type(4))) unsigned uint4v;
typedef __attribute__((ext_vector_type(4))) unsigned short ushort4v;

__device__ inline unsigned short f2bf(float f) {
    unsigned u = __builtin_bit_cast(unsigned, f);
    u += 0x7FFFu + ((u >> 16) & 1u);   // RNE
    return (unsigned short)(u >> 16);
}

__device__ inline short8 cvt8(float4v lo, float4v hi) {
    uint4v u;
    asm("v_cvt_pk_bf16_f32 %0, %1, %2" : "=v"(u[0]) : "v"(lo[0]), "v"(lo[1]));
    asm("v_cvt_pk_bf16_f32 %0, %1, %2" : "=v"(u[1]) : "v"(lo[2]), "v"(lo[3]));
    asm("v_cvt_pk_bf16_f32 %0, %1, %2" : "=v"(u[2]) : "v"(hi[0]), "v"(hi[1]));
    asm("v_cvt_pk_bf16_f32 %0, %1, %2" : "=v"(u[3]) : "v"(hi[2]), "v"(hi[3]));
    return __builtin_bit_cast(short8, u);
}

__device__ inline float fast_exp2(float x) {
    float r;
    asm("v_exp_f32 %0, %1" : "=v"(r) : "v"(x));
    return r;
}
__device__ inline float fast_expf(float x) { return fast_exp2(x * 1.4426950408889634f); }
__device__ inline float fast_tanh(float x) {
    float y = x * 2.8853900817779268f;          // 2x * log2(e)
    y = fminf(fmaxf(y, -30.f), 30.f);
    float t = fast_exp2(y);
    float r;
    asm("v_rcp_f32 %0, %1" : "=v"(r) : "v"(t + 1.f));
    return (t - 1.f) * r;
}

// LDS-only barrier: orders LDS traffic without draining vmcnt.
#define SYNC_LDS() do { asm volatile("s_waitcnt lgkmcnt(0)" ::: "memory"); \
                        __builtin_amdgcn_s_barrier(); \
                        asm volatile("" ::: "memory"); } while (0)
#define WAITV8()  asm volatile("s_waitcnt vmcnt(8)" ::: "memory")
#define WAITV0()  asm volatile("s_waitcnt vmcnt(0)" ::: "memory")
#define BARRIER() do { __builtin_amdgcn_s_barrier(); asm volatile("" ::: "memory"); } while (0)

__device__ inline void load_lds16(const void* g, void* l) {
    __builtin_amdgcn_global_load_lds(
        (const __attribute__((address_space(1))) void*)g,
        (__attribute__((address_space(3))) void*)l, 16, 0, 0);
}

// stage one 64-row f32 sub-tile; wave stages rows [wave*8, wave*8+8).
// Source pre-swizzled on 32B granules (g ^= r&7); LDS dest linear (rule 21).
__device__ inline void stage(const float* qtile, float* buf, int wave, int lane) {
    const int half = lane & 1;
    #pragma unroll
    for (int i = 0; i < 8; ++i) {
        int r = wave * 8 + i;
        int gsrc = ((((lane >> 1) ^ (r & 7)) << 1) | half) << 4;   // byte in row
        load_lds16((const char*)qtile + (size_t)r * 1024 + gsrc,
                   (char*)buf + r * 1024);
    }
}

// ---------------- kernel 0 (fused prep): W1 f32->bf16  AND  g23 ----------------
__global__ __launch_bounds__(256) void k_prep(const float* __restrict__ W1,
                                              unsigned short* __restrict__ w1b,
                                              const float* __restrict__ ctx,
                                              const float* __restrict__ hid,
                                              const float* __restrict__ W2,
                                              const float* __restrict__ b2,
                                              const float* __restrict__ W3,
                                              float* __restrict__ g23) {
    if (blockIdx.x < 64) {
        int i = blockIdx.x * 256 + threadIdx.x;
        float4v v = ((const float4v*)W1)[i];
        ushort4v o;
        o[0] = f2bf(v[0]); o[1] = f2bf(v[1]); o[2] = f2bf(v[2]); o[3] = f2bf(v[3]);
        ((ushort4v*)w1b)[i] = o;
    } else {
        int b = blockIdx.x - 64, t = threadIdx.x;
        __shared__ float c[HD], hh[HD];
        c[t]  = ctx[b * HD + t];
        hh[t] = hid[b * HD + t];
        __syncthreads();
        const float4v* w2 = (const float4v*)(W2 + (size_t)t * HD);
        const float4v* w3 = (const float4v*)(W3 + (size_t)t * HD);
        float acc = b2[t];
        #pragma unroll 8
        for (int k = 0; k < 64; ++k) {
            float4v a = w2[k], d = w3[k];
            int k4 = k * 4;
            acc += c[k4] * a[0] + c[k4 + 1] * a[1] + c[k4 + 2] * a[2] + c[k4 + 3] * a[3];
            acc += hh[k4] * d[0] + hh[k4 + 1] * d[1] + hh[k4 + 2] * d[2] + hh[k4 + 3] * d[3];
        }
        g23[b * HD + t] = acc;
    }
}

// ---------------- kernel 1: fused pipeline (r8 skeleton + bounded-exp) ---------
// grid (4, 64) = 256 blocks = 1/CU. 512 thr, 8 waves; wave owns 32 h
// (bfr = 64 VGPR, the proven non-spilling config). Per 64-row sub-tile:
// gload_lds f32 (src-swizzled) -> counted vmcnt(8) -> MFMA C[h][d] -> tanh.W4
// partials -> B3 -> passB: PLAIN exp (|s|<=sum|W4|~8, fp32-safe: no max
// chains, no rescale) + PV from f32 tile. 8.4x less serial chain than r8 passB.
__global__ __launch_bounds__(512) void k_fused(const float* __restrict__ q,
                                               const unsigned short* __restrict__ w1b,
                                               const float* __restrict__ g23,
                                               const float* __restrict__ W4,
                                               float* __restrict__ pl,
                                               float* __restrict__ pO) {
    __shared__ __attribute__((aligned(16))) float buf0[64 * HD];   // 64 KB
    __shared__ __attribute__((aligned(16))) float buf1[64 * HD];   // 64 KB
    __shared__ float sp[8][64];

    const int t = threadIdx.x;
    const int qtr = blockIdx.x, b = blockIdx.y;
    const int lane = t & 63, wave = t >> 6;
    const int l15 = lane & 15, lk = lane >> 4;
    const int hb = wave * 32;
    const int cq = lane & 7, ro = lane >> 3;   // PV: col-quad, row-oct

    const float* qq = q + ((size_t)b * DD + qtr * 512) * HD;

    // issue sub-tile 0 immediately
    stage(qq, buf0, wave, lane);

    // W1 slice -> 64 VGPR (L2-hot after k_prep)
    short8 bfr[8][2];
    #pragma unroll
    for (int kb = 0; kb < 8; ++kb)
        #pragma unroll
        for (int nf = 0; nf < 2; ++nf)
            bfr[kb][nf] = *(const short8*)&w1b[(size_t)(hb + nf * 16 + l15) * HD + kb * 32 + lk * 8];

    // per-lane g23/W4 for C rows h = hb + nf*16 + lk*4 + r
    float gv[2][4], wv[2][4];
    #pragma unroll
    for (int nf = 0; nf < 2; ++nf)
        #pragma unroll
        for (int r = 0; r < 4; ++r) {
            int h = hb + nf * 16 + lk * 4 + r;
            gv[nf][r] = g23[b * HD + h];
            wv[nf][r] = W4[h];
        }

    float l = 0.f;
    float4v O = {0.f, 0.f, 0.f, 0.f};
    float* cur = buf0;
    float* nxt = buf1;

    #pragma unroll 1
    for (int st = 0; st < NST; ++st) {
        SYNC_LDS();                      // B1: all waves done reading nxt (prev iter)
        if (st + 1 < NST) {
            stage(qq + (size_t)(st + 1) * 64 * HD, nxt, wave, lane);
            WAITV8();                    // drain cur's 8 loads; nxt's 8 stay in flight
        } else {
            WAITV0();
        }
        BARRIER();                       // B2: cur fully staged by all waves

        // ---- passA: partial scores for all 64 rows x this wave's 32 h ----
        #pragma unroll
        for (int mf = 0; mf < 4; ++mf) {
            float4v acc0 = {0.f, 0.f, 0.f, 0.f}, acc1 = {0.f, 0.f, 0.f, 0.f};
            const int d = mf * 16 + l15;
            const int dsw = d & 7;
            #pragma unroll
            for (int kb = 0; kb < 8; ++kb) {
                int g = kb * 4 + lk;                       // 32B k-granule
                int byte = d * 1024 + ((g ^ dsw) << 5);
                float4v lo = *(const float4v*)((const char*)cur + byte);
                float4v hi = *(const float4v*)((const char*)cur + byte + 16);
                short8 bq = cvt8(lo, hi);
                acc0 = __builtin_amdgcn_mfma_f32_16x16x32_bf16(bfr[kb][0], bq, acc0, 0, 0, 0);
                acc1 = __builtin_amdgcn_mfma_f32_16x16x32_bf16(bfr[kb][1], bq, acc1, 0, 0, 0);
            }
            float s = 0.f;
            #pragma unroll
            for (int r = 0; r < 4; ++r) s += fast_tanh(acc0[r] + gv[0][r]) * wv[0][r];
            #pragma unroll
            for (int r = 0; r < 4; ++r) s += fast_tanh(acc1[r] + gv[1][r]) * wv[1][r];
            s += __shfl_xor(s, 16, 64);
            s += __shfl_xor(s, 32, 64);
            if (lk == 0) sp[wave][mf * 16 + l15] = s;
        }
        SYNC_LDS();                      // B3: sp published

        // ---- passB: bounded exp (no max chains, no rescale) + PV ----
        float sc = sp[0][lane] + sp[1][lane] + sp[2][lane] + sp[3][lane]
                 + sp[4][lane] + sp[5][lane] + sp[6][lane] + sp[7][lane];
        float w = fast_exp2(sc * 1.4426950408889634f);
        l += w;                          // lane's row = lane; summed across lanes at end
        // PV: cols wave*32 + cq*4, rows d = ro*8 + i (f32 tile, swizzled granules)
        const int gq = wave * 4 + (cq >> 1);
        const int hoff = (cq & 1) << 4;
        #pragma unroll
        for (int i = 0; i < 8; ++i) {
            int d = ro * 8 + i;
            float wd = __shfl(w, d, 64);
            int byte = d * 1024 + ((gq ^ (d & 7)) << 5) + hoff;
            float4v v = *(const float4v*)((const char*)cur + byte);
            O += wd * v;
        }

        float* tmp = cur; cur = nxt; nxt = tmp;
    }

    // reduce O over the 8 row-octs (lanes sharing cq)
    #pragma unroll
    for (int j = 0; j < 4; ++j) {
        O[j] += __shfl_xor(O[j], 8, 64);
        O[j] += __shfl_xor(O[j], 16, 64);
        O[j] += __shfl_xor(O[j], 32, 64);
    }
    if (ro == 0)
        *(float4v*)&pO[((size_t)(b * NQ + qtr)) * HD + wave * 32 + cq * 4] = O;

    // reduce l over 64 lanes (identical across waves); one write
    l += __shfl_xor(l, 1, 64);
    l += __shfl_xor(l, 2, 64);
    l += __shfl_xor(l, 4, 64);
    l += __shfl_xor(l, 8, 64);
    l += __shfl_xor(l, 16, 64);
    l += __shfl_xor(l, 32, 64);
    if (t == 0) pl[b * NQ + qtr] = l;
}

// ---------------- kernel 2: combine 4 quarter-partials per batch ---------------
__global__ __launch_bounds__(256) void k_comb(const float* __restrict__ pl,
                                              const float* __restrict__ pO,
                                              float* __restrict__ out) {
    int b = blockIdx.x, t = threadIdx.x;
    float L = pl[b * NQ] + pl[b * NQ + 1] + pl[b * NQ + 2] + pl[b * NQ + 3];
    float s = 0.f;
    #pragma unroll
    for (int c = 0; c < NQ; ++c) s += pO[((size_t)(b * NQ + c)) * HD + t];
    out[b * HD + t] = s / L;
}

extern "C" void kernel_launch(void* const* d_in, const int* in_sizes, int n_in,
                              void* d_out, int out_size, void* d_ws, size_t ws_size,
                              hipStream_t stream) {
    (void)in_sizes; (void)n_in; (void)out_size; (void)ws_size;
    const float* ctx = (const float*)d_in[0];
    const float* q   = (const float*)d_in[1];
    const float* hid = (const float*)d_in[2];
    const float* W1  = (const float*)d_in[3];
    const float* W2  = (const float*)d_in[4];
    const float* b2  = (const float*)d_in[5];
    const float* W3  = (const float*)d_in[6];
    const float* W4  = (const float*)d_in[7];
    // d_in[8] = b4: cancels exactly in exp-sum ratio (softmax shift-invariance)
    float* out = (float*)d_out;

    char* ws = (char*)d_ws;
    unsigned short* w1b = (unsigned short*)(ws);            // 131072 B
    float* g23 = (float*)(ws + 131072);                     //  65536 B
    float* pl  = (float*)(ws + 196608);                     //   1024 B
    float* pO  = (float*)(ws + 197632);                     // 262144 B

    k_prep <<<dim3(128), dim3(256), 0, stream>>>(W1, w1b, ctx, hid, W2, b2, W3, g23);
    k_fused<<<dim3(NQ, BB), dim3(512), 0, stream>>>(q, w1b, g23, W4, pl, pO);
    k_comb <<<dim3(BB), dim3(256), 0, stream>>>(pl, pO, out);
}